// Round 1
// baseline (300.635 us; speedup 1.0000x reference)
//
#include <hip/hip_runtime.h>

#define N_NODES 100000
#define N_EDGES 1600000
#define D 128
#define NB 196              // buckets of 512 nodes: 196*512 = 100352 >= N_NODES
#define EPT 10              // edges per thread in binning
#define CHUNK 2560          // 256 threads * EPT
#define BIN_BLOCKS 625      // 625 * 2560 = 1,600,000 exactly
#define CVT_X_BLOCKS 6250   // 6250*256*8 = 12.8M elements

typedef __bf16 bf16x8 __attribute__((ext_vector_type(8)));
typedef float f32x4 __attribute__((ext_vector_type(4)));

__device__ __forceinline__ unsigned f2bf(float f) {
    unsigned u = __float_as_uint(f);
    return (u + 0x7fffu + ((u >> 16) & 1u)) >> 16;   // RNE
}
__device__ __forceinline__ float bf_lo(unsigned u) { return __uint_as_float(u << 16); }
__device__ __forceinline__ float bf_hi(unsigned u) { return __uint_as_float(u & 0xffff0000u); }

// ---------------- fused: x->bf16 (row-major) + Wt build + bucket histogram ----------------
__global__ __launch_bounds__(256) void prep_kernel(const float* __restrict__ x,
                                                   const float* __restrict__ Wrel,
                                                   const float* __restrict__ Wroot,
                                                   const int* __restrict__ ei,
                                                   unsigned short* __restrict__ x_bf,
                                                   unsigned short* __restrict__ Wt,
                                                   int* __restrict__ bcount) {
    __shared__ int h[256];
    int b = blockIdx.x;
    int t = threadIdx.x;
    if (b < CVT_X_BLOCKS) {
        size_t i = ((size_t)b * 256 + t) * 8;
        float4 v0 = *(const float4*)(x + i);
        float4 v1 = *(const float4*)(x + i + 4);
        uint4 p;
        p.x = f2bf(v0.x) | (f2bf(v0.y) << 16);
        p.y = f2bf(v0.z) | (f2bf(v0.w) << 16);
        p.z = f2bf(v1.x) | (f2bf(v1.y) << 16);
        p.w = f2bf(v1.z) | (f2bf(v1.w) << 16);
        *(uint4*)(x_bf + i) = p;
    } else if (b < CVT_X_BLOCKS + 128) {
        int c = b - CVT_X_BLOCKS;          // 0..127
        float v = (t < 128) ? Wrel[t * D + c] : Wroot[(t - 128) * D + c];
        Wt[c * 256 + t] = (unsigned short)f2bf(v);
    } else {
        int blk = b - (CVT_X_BLOCKS + 128);
        h[t] = 0;
        __syncthreads();
        int base = blk * CHUNK;
#pragma unroll
        for (int i = 0; i < EPT; ++i) {
            int dst = ei[N_EDGES + base + i * 256 + t];
            atomicAdd(&h[dst >> 9], 1);
        }
        __syncthreads();
        if (t < NB && h[t]) atomicAdd(&bcount[t], h[t]);
    }
}

// ---------------- bucket scan (1 block) ----------------
__global__ __launch_bounds__(256) void bscan_kernel(const int* __restrict__ bcount,
                                                    int* __restrict__ bucket_base,
                                                    int* __restrict__ bcur) {
    __shared__ int s[256];
    int t = threadIdx.x;
    int v = (t < NB) ? bcount[t] : 0;
    s[t] = v;
    __syncthreads();
    for (int off = 1; off < 256; off <<= 1) {
        int a = (t >= off) ? s[t - off] : 0;
        __syncthreads();
        s[t] += a;
        __syncthreads();
    }
    int excl = s[t] - v;
    if (t < NB) {
        bucket_base[t] = excl;
        bcur[t] = excl;
    }
    if (t == NB) bucket_base[NB] = N_EDGES;
}

// ---------------- binify: block-local multisplit -> packed 4B edge codes ----------------
// code: src in bits 0..16, local dst (dst&511) in bits 17..25
__global__ __launch_bounds__(256) void binify_kernel(const int* __restrict__ ei,
                                                     int* __restrict__ bcur,
                                                     unsigned* __restrict__ epk) {
    __shared__ int lhist[256];
    __shared__ int lstart[256];
    __shared__ int lfill[256];
    __shared__ int gbase[256];
    __shared__ uint2 stage[CHUNK];

    int t = threadIdx.x;
    int base = blockIdx.x * CHUNK;
    lhist[t] = 0;
    lfill[t] = 0;
    __syncthreads();

    int src[EPT], dst[EPT];
#pragma unroll
    for (int i = 0; i < EPT; ++i) {
        int e = base + i * 256 + t;
        src[i] = ei[e];
        dst[i] = ei[N_EDGES + e];
        atomicAdd(&lhist[dst[i] >> 9], 1);
    }
    __syncthreads();

    int v = lhist[t];
    lstart[t] = v;
    __syncthreads();
    for (int off = 1; off < 256; off <<= 1) {
        int a = (t >= off) ? lstart[t - off] : 0;
        __syncthreads();
        lstart[t] += a;
        __syncthreads();
    }
    int excl = lstart[t] - v;
    if (t < NB && v > 0) gbase[t] = atomicAdd(&bcur[t], v);
    __syncthreads();
    lstart[t] = excl;
    __syncthreads();

#pragma unroll
    for (int i = 0; i < EPT; ++i) {
        int b = dst[i] >> 9;
        int lp = atomicAdd(&lfill[b], 1);
        stage[lstart[b] + lp] = make_uint2((unsigned)src[i], (unsigned)dst[i]);
    }
    __syncthreads();

    for (int i = t; i < CHUNK; i += 256) {
        uint2 p = stage[i];
        int b = (int)(p.y >> 9);
        unsigned code = p.x | ((p.y & 511u) << 17);
        epk[gbase[b] + (i - lstart[b])] = code;
    }
}

// ---------------- place: per-bucket local count+scan -> rowstart, srcs ----------------
__global__ __launch_bounds__(256) void place_kernel(const unsigned* __restrict__ epk,
                                                    const int* __restrict__ bucket_base,
                                                    int* __restrict__ rowstart,
                                                    int* __restrict__ srcs) {
    __shared__ int bufA[512];
    __shared__ int bufB[512];
    int b = blockIdx.x;
    int t = threadIdx.x;
    int pbeg = bucket_base[b];
    int pend = bucket_base[b + 1];

    bufA[t] = 0;
    bufA[t + 256] = 0;
    __syncthreads();
    for (int i = pbeg + t; i < pend; i += 256)
        atomicAdd(&bufA[epk[i] >> 17], 1);
    __syncthreads();

    for (int j = t; j < 512; j += 256) bufB[j] = j ? bufA[j - 1] : 0;
    __syncthreads();
    int* cur = bufB;
    int* nxt = bufA;
    for (int off = 1; off < 512; off <<= 1) {
        for (int j = t; j < 512; j += 256)
            nxt[j] = cur[j] + ((j >= off) ? cur[j - off] : 0);
        __syncthreads();
        int* tmp = cur; cur = nxt; nxt = tmp;
    }

    for (int j = t; j < 512; j += 256) {
        int gnode = (b << 9) + j;
        int val = pbeg + cur[j];
        if (gnode <= N_NODES) rowstart[gnode] = val;
        nxt[j] = val;
    }
    __syncthreads();

    for (int i = pbeg + t; i < pend; i += 256) {
        unsigned code = epk[i];
        int pos = atomicAdd(&nxt[code >> 17], 1);
        srcs[pos] = (int)(code & 0x1FFFFu);
    }
}

// ---------------- gather: ONE node per 64-lane wave, divergence-free ----------------
// lanes<32 take even edges, lanes>=32 take odd edges of the SAME node; trip count is
// wave-uniform so no exec-masked wasted iterations. 8 x 512B loads in flight per iter
// (16 edges). Cross-half combine via shfl_xor(.,32) at the end.
__global__ __launch_bounds__(256) void gather_kernel(const unsigned short* __restrict__ x_bf,
                                                     const int* __restrict__ rowstart,
                                                     const int* __restrict__ srcs,
                                                     unsigned short* __restrict__ aggr_bf) {
    int t = threadIdx.x;
    int node = blockIdx.x * 4 + (t >> 6);
    int lane = t & 63;
    int half = lane >> 5;          // 0: even edges, 1: odd edges
    int l32 = lane & 31;
    int begin = rowstart[node];
    int end = rowstart[node + 1];
    const unsigned short* xp = x_bf + l32 * 4;
    float a0 = 0.f, a1 = 0.f, a2 = 0.f, a3 = 0.f;
    int e = begin;
    // main loop: 16 edges per iteration, this half handles 8 (stride-2)
    for (; e + 15 < end; e += 16) {
        int s0 = srcs[e + 0 + half];
        int s1 = srcs[e + 2 + half];
        int s2 = srcs[e + 4 + half];
        int s3 = srcs[e + 6 + half];
        int s4 = srcs[e + 8 + half];
        int s5 = srcs[e + 10 + half];
        int s6 = srcs[e + 12 + half];
        int s7 = srcs[e + 14 + half];
        uint2 u0 = *(const uint2*)(xp + (size_t)s0 * D);
        uint2 u1 = *(const uint2*)(xp + (size_t)s1 * D);
        uint2 u2 = *(const uint2*)(xp + (size_t)s2 * D);
        uint2 u3 = *(const uint2*)(xp + (size_t)s3 * D);
        uint2 u4 = *(const uint2*)(xp + (size_t)s4 * D);
        uint2 u5 = *(const uint2*)(xp + (size_t)s5 * D);
        uint2 u6 = *(const uint2*)(xp + (size_t)s6 * D);
        uint2 u7 = *(const uint2*)(xp + (size_t)s7 * D);
        a0 += bf_lo(u0.x) + bf_lo(u1.x) + bf_lo(u2.x) + bf_lo(u3.x)
            + bf_lo(u4.x) + bf_lo(u5.x) + bf_lo(u6.x) + bf_lo(u7.x);
        a1 += bf_hi(u0.x) + bf_hi(u1.x) + bf_hi(u2.x) + bf_hi(u3.x)
            + bf_hi(u4.x) + bf_hi(u5.x) + bf_hi(u6.x) + bf_hi(u7.x);
        a2 += bf_lo(u0.y) + bf_lo(u1.y) + bf_lo(u2.y) + bf_lo(u3.y)
            + bf_lo(u4.y) + bf_lo(u5.y) + bf_lo(u6.y) + bf_lo(u7.y);
        a3 += bf_hi(u0.y) + bf_hi(u1.y) + bf_hi(u2.y) + bf_hi(u3.y)
            + bf_hi(u4.y) + bf_hi(u5.y) + bf_hi(u6.y) + bf_hi(u7.y);
    }
    // pair tail: 2 edges per iteration, one per half
    for (; e + 1 < end; e += 2) {
        int s = srcs[e + half];
        uint2 u = *(const uint2*)(xp + (size_t)s * D);
        a0 += bf_lo(u.x);
        a1 += bf_hi(u.x);
        a2 += bf_lo(u.y);
        a3 += bf_hi(u.y);
    }
    // single remainder (half 0 only)
    if (e < end && half == 0) {
        uint2 u = *(const uint2*)(xp + (size_t)srcs[e] * D);
        a0 += bf_lo(u.x);
        a1 += bf_hi(u.x);
        a2 += bf_lo(u.y);
        a3 += bf_hi(u.y);
    }
    // combine halves
    a0 += __shfl_xor(a0, 32);
    a1 += __shfl_xor(a1, 32);
    a2 += __shfl_xor(a2, 32);
    a3 += __shfl_xor(a3, 32);
    if (half == 0) {
        uint2 w;
        w.x = f2bf(a0) | (f2bf(a1) << 16);
        w.y = f2bf(a2) | (f2bf(a3) << 16);
        *(uint2*)(aggr_bf + (size_t)node * D + l32 * 4) = w;
    }
}

// ---------------- MFMA GEMM + fused BN stats; h stored bf16 ----------------
#define LDSTRIDE 40
__global__ __launch_bounds__(256) void gemm_mfma(const unsigned short* __restrict__ aggr_bf,
                                                 const unsigned short* __restrict__ x_bf,
                                                 const unsigned short* __restrict__ Wt,
                                                 const float* __restrict__ brel,
                                                 unsigned short* __restrict__ h_bf,
                                                 float* __restrict__ gsum,
                                                 float* __restrict__ gss) {
    __shared__ unsigned short As[128][LDSTRIDE];
    __shared__ unsigned short Bs[128][LDSTRIDE];
    __shared__ float sbias[128];
    __shared__ float SredS[4][128];
    __shared__ float SredQ[4][128];

    const int t = threadIdx.x;
    const int wave = t >> 6;
    const int lane = t & 63;
    const int quad = lane >> 4;
    const int l16 = lane & 15;
    const int blockRow = blockIdx.x * 128;

    if (t < 128) sbias[t] = brel[t];

    f32x4 acc[2][8];
#pragma unroll
    for (int i = 0; i < 2; ++i)
#pragma unroll
        for (int j = 0; j < 8; ++j) acc[i][j] = (f32x4){0.f, 0.f, 0.f, 0.f};

    for (int kc = 0; kc < 8; ++kc) {
        const unsigned short* Asrc = (kc < 4) ? aggr_bf : x_bf;
        const int k0 = (kc & 3) * 32;
#pragma unroll
        for (int s = t; s < 512; s += 256) {
            int row = s >> 2;
            int q = (s & 3) * 8;
            int grow = blockRow + row;
            uint4 v = make_uint4(0, 0, 0, 0);
            if (grow < N_NODES) v = *(const uint4*)(Asrc + (size_t)grow * D + k0 + q);
            *(uint4*)&As[row][q] = v;
        }
#pragma unroll
        for (int s = t; s < 512; s += 256) {
            int col = s >> 2;
            int q = (s & 3) * 8;
            uint4 v = *(const uint4*)(Wt + col * 256 + kc * 32 + q);
            *(uint4*)&Bs[col][q] = v;
        }
        __syncthreads();

        bf16x8 afrag0 = *(bf16x8*)&As[wave * 32 + l16][quad * 8];
        bf16x8 afrag1 = *(bf16x8*)&As[wave * 32 + 16 + l16][quad * 8];
#pragma unroll
        for (int ct = 0; ct < 8; ++ct) {
            bf16x8 bfrag = *(bf16x8*)&Bs[ct * 16 + l16][quad * 8];
            acc[0][ct] = __builtin_amdgcn_mfma_f32_16x16x32_bf16(afrag0, bfrag, acc[0][ct], 0, 0, 0);
            acc[1][ct] = __builtin_amdgcn_mfma_f32_16x16x32_bf16(afrag1, bfrag, acc[1][ct], 0, 0, 0);
        }
        __syncthreads();
    }

    float csum[8], css[8];
#pragma unroll
    for (int ct = 0; ct < 8; ++ct) { csum[ct] = 0.f; css[ct] = 0.f; }

#pragma unroll
    for (int rt = 0; rt < 2; ++rt) {
#pragma unroll
        for (int ct = 0; ct < 8; ++ct) {
            int col = ct * 16 + l16;
            float bv = sbias[col];
#pragma unroll
            for (int reg = 0; reg < 4; ++reg) {
                int row = blockRow + wave * 32 + rt * 16 + quad * 4 + reg;
                if (row < N_NODES) {
                    float v = acc[rt][ct][reg] + bv;
                    h_bf[(size_t)row * D + col] = (unsigned short)f2bf(v);
                    csum[ct] += v;
                    css[ct] += v * v;
                }
            }
        }
    }
#pragma unroll
    for (int ct = 0; ct < 8; ++ct) {
        float s = csum[ct], q = css[ct];
        s += __shfl_xor(s, 16);
        s += __shfl_xor(s, 32);
        q += __shfl_xor(q, 16);
        q += __shfl_xor(q, 32);
        if (quad == 0) {
            SredS[wave][ct * 16 + l16] = s;
            SredQ[wave][ct * 16 + l16] = q;
        }
    }
    __syncthreads();
    if (t < 128) {
        float s = SredS[0][t] + SredS[1][t] + SredS[2][t] + SredS[3][t];
        float q = SredQ[0][t] + SredQ[1][t] + SredQ[2][t] + SredQ[3][t];
        unsafeAtomicAdd(&gsum[t], s);
        unsafeAtomicAdd(&gss[t], q);
    }
}

// ---------------- normalize + relu: read h_bf, write f32 out ----------------
__global__ __launch_bounds__(256) void norm_kernel(const unsigned short* __restrict__ h_bf,
                                                   float* __restrict__ out,
                                                   const float* __restrict__ gsum,
                                                   const float* __restrict__ gss,
                                                   const float* __restrict__ gamma,
                                                   const float* __restrict__ beta) {
    __shared__ float sscale[128];
    __shared__ float sshift[128];
    int t = threadIdx.x;
    if (t < 128) {
        const float inv_n = 1.0f / (float)N_NODES;
        float mean = gsum[t] * inv_n;
        float var = gss[t] * inv_n - mean * mean;
        float rs = rsqrtf(var + 1e-5f);
        float sc = gamma[t] * rs;
        sscale[t] = sc;
        sshift[t] = beta[t] - mean * sc;
    }
    __syncthreads();
    size_t e = ((size_t)blockIdx.x * 256 + t) * 4;
    if (e >= (size_t)N_NODES * D) return;
    int c = (int)(e & 127);
    uint2 u = *(const uint2*)(h_bf + e);
    float4 v;
    v.x = fmaxf(bf_lo(u.x) * sscale[c + 0] + sshift[c + 0], 0.f);
    v.y = fmaxf(bf_hi(u.x) * sscale[c + 1] + sshift[c + 1], 0.f);
    v.z = fmaxf(bf_lo(u.y) * sscale[c + 2] + sshift[c + 2], 0.f);
    v.w = fmaxf(bf_hi(u.y) * sscale[c + 3] + sshift[c + 3], 0.f);
    *(float4*)(out + e) = v;
}

extern "C" void kernel_launch(void* const* d_in, const int* in_sizes, int n_in,
                              void* d_out, int out_size, void* d_ws, size_t ws_size,
                              hipStream_t stream) {
    const float* x     = (const float*)d_in[0];
    const int*   ei    = (const int*)d_in[1];
    const float* Wroot = (const float*)d_in[2];
    const float* Wrel  = (const float*)d_in[3];
    const float* brel  = (const float*)d_in[4];
    const float* gamma = (const float*)d_in[5];
    const float* beta  = (const float*)d_in[6];
    float* out = (float*)d_out;

    // workspace layout; h_bf aliases (epk,srcs) which are dead by gemm time
    unsigned short* aggr_bf = (unsigned short*)d_ws;            // N*D (25.6 MB)
    unsigned short* x_bf    = aggr_bf + (size_t)N_NODES * D;    // N*D (25.6 MB)
    unsigned short* Wt      = x_bf + (size_t)N_NODES * D;       // 128*256
    float* gsum  = (float*)(Wt + 128 * 256);                    // 128 ─┐
    float* gss   = gsum + 128;                                  // 128  │ zeroed
    int* bcount  = (int*)(gss + 128);                           // 256 ─┘
    int* bucket_base = bcount + 256;                            // 256 (197 used)
    int* bcur    = bucket_base + 256;                           // 256
    int* rowstart = bcur + 256;                                 // 100352
    unsigned* epk = (unsigned*)(rowstart + 100352);             // N_EDGES (6.4 MB)
    int* srcs    = (int*)(epk + N_EDGES);                       // N_EDGES (6.4 MB)
    unsigned short* h_bf = (unsigned short*)epk;                // N*D (25.6 MB) alias

    hipMemsetAsync(gsum, 0, 512 * sizeof(int), stream);

    prep_kernel<<<CVT_X_BLOCKS + 128 + BIN_BLOCKS, 256, 0, stream>>>(
        x, Wrel, Wroot, ei, x_bf, Wt, bcount);
    bscan_kernel<<<1, 256, 0, stream>>>(bcount, bucket_base, bcur);
    binify_kernel<<<BIN_BLOCKS, 256, 0, stream>>>(ei, bcur, epk);
    place_kernel<<<NB, 256, 0, stream>>>(epk, bucket_base, rowstart, srcs);
    gather_kernel<<<N_NODES / 4, 256, 0, stream>>>(x_bf, rowstart, srcs, aggr_bf);
    gemm_mfma<<<(N_NODES + 127) / 128, 256, 0, stream>>>(aggr_bf, x_bf, Wt, brel, h_bf, gsum, gss);
    norm_kernel<<<12500, 256, 0, stream>>>(h_bf, out, gsum, gss, gamma, beta);
}

// Round 2
// 287.813 us; speedup vs baseline: 1.0446x; 1.0446x over previous
//
#include <hip/hip_runtime.h>

#define N_NODES 100000
#define N_EDGES 1600000
#define D 128
#define NB 196              // buckets of 512 nodes: 196*512 = 100352 >= N_NODES
#define EPT 10              // edges per thread in binning
#define CHUNK 2560          // 256 threads * EPT
#define BIN_BLOCKS 625      // 625 * 2560 = 1,600,000 exactly
#define CVT_X_BLOCKS 6250   // 6250*256*8 = 12.8M elements
#define ZROW N_NODES        // index of the zeroed padding row in x_bf

typedef __bf16 bf16x8 __attribute__((ext_vector_type(8)));
typedef float f32x4 __attribute__((ext_vector_type(4)));

__device__ __forceinline__ unsigned f2bf(float f) {
    unsigned u = __float_as_uint(f);
    return (u + 0x7fffu + ((u >> 16) & 1u)) >> 16;   // RNE
}
__device__ __forceinline__ float bf_lo(unsigned u) { return __uint_as_float(u << 16); }
__device__ __forceinline__ float bf_hi(unsigned u) { return __uint_as_float(u & 0xffff0000u); }

// ---------------- fused: x->bf16 (row-major) + Wt build + zero-row + bucket histogram ----------------
__global__ __launch_bounds__(256) void prep_kernel(const float* __restrict__ x,
                                                   const float* __restrict__ Wrel,
                                                   const float* __restrict__ Wroot,
                                                   const int* __restrict__ ei,
                                                   unsigned short* __restrict__ x_bf,
                                                   unsigned short* __restrict__ Wt,
                                                   int* __restrict__ bcount) {
    __shared__ int h[256];
    int b = blockIdx.x;
    int t = threadIdx.x;
    if (b < CVT_X_BLOCKS) {
        size_t i = ((size_t)b * 256 + t) * 8;
        float4 v0 = *(const float4*)(x + i);
        float4 v1 = *(const float4*)(x + i + 4);
        uint4 p;
        p.x = f2bf(v0.x) | (f2bf(v0.y) << 16);
        p.y = f2bf(v0.z) | (f2bf(v0.w) << 16);
        p.z = f2bf(v1.x) | (f2bf(v1.y) << 16);
        p.w = f2bf(v1.z) | (f2bf(v1.w) << 16);
        *(uint4*)(x_bf + i) = p;
    } else if (b < CVT_X_BLOCKS + 128) {
        int c = b - CVT_X_BLOCKS;          // 0..127
        float v = (t < 128) ? Wrel[t * D + c] : Wroot[(t - 128) * D + c];
        Wt[c * 256 + t] = (unsigned short)f2bf(v);
    } else if (b == CVT_X_BLOCKS + 128) {
        // zero the padding row x_bf[N_NODES]: 128 shorts = 16 uint4
        if (t < 16) *(uint4*)(x_bf + (size_t)ZROW * D + t * 8) = make_uint4(0, 0, 0, 0);
    } else {
        int blk = b - (CVT_X_BLOCKS + 129);
        h[t] = 0;
        __syncthreads();
        int base = blk * CHUNK;
#pragma unroll
        for (int i = 0; i < EPT; ++i) {
            int dst = ei[N_EDGES + base + i * 256 + t];
            atomicAdd(&h[dst >> 9], 1);
        }
        __syncthreads();
        if (t < NB && h[t]) atomicAdd(&bcount[t], h[t]);
    }
}

// ---------------- bucket scan (1 block) ----------------
__global__ __launch_bounds__(256) void bscan_kernel(const int* __restrict__ bcount,
                                                    int* __restrict__ bucket_base,
                                                    int* __restrict__ bcur) {
    __shared__ int s[256];
    int t = threadIdx.x;
    int v = (t < NB) ? bcount[t] : 0;
    s[t] = v;
    __syncthreads();
    for (int off = 1; off < 256; off <<= 1) {
        int a = (t >= off) ? s[t - off] : 0;
        __syncthreads();
        s[t] += a;
        __syncthreads();
    }
    int excl = s[t] - v;
    if (t < NB) {
        bucket_base[t] = excl;
        bcur[t] = excl;
    }
    if (t == NB) bucket_base[NB] = N_EDGES;
}

// ---------------- binify: block-local multisplit -> packed 4B edge codes ----------------
// code: src in bits 0..16, local dst (dst&511) in bits 17..25
__global__ __launch_bounds__(256) void binify_kernel(const int* __restrict__ ei,
                                                     int* __restrict__ bcur,
                                                     unsigned* __restrict__ epk) {
    __shared__ int lhist[256];
    __shared__ int lstart[256];
    __shared__ int lfill[256];
    __shared__ int gbase[256];
    __shared__ uint2 stage[CHUNK];

    int t = threadIdx.x;
    int base = blockIdx.x * CHUNK;
    lhist[t] = 0;
    lfill[t] = 0;
    __syncthreads();

    int src[EPT], dst[EPT];
#pragma unroll
    for (int i = 0; i < EPT; ++i) {
        int e = base + i * 256 + t;
        src[i] = ei[e];
        dst[i] = ei[N_EDGES + e];
        atomicAdd(&lhist[dst[i] >> 9], 1);
    }
    __syncthreads();

    int v = lhist[t];
    lstart[t] = v;
    __syncthreads();
    for (int off = 1; off < 256; off <<= 1) {
        int a = (t >= off) ? lstart[t - off] : 0;
        __syncthreads();
        lstart[t] += a;
        __syncthreads();
    }
    int excl = lstart[t] - v;
    if (t < NB && v > 0) gbase[t] = atomicAdd(&bcur[t], v);
    __syncthreads();
    lstart[t] = excl;
    __syncthreads();

#pragma unroll
    for (int i = 0; i < EPT; ++i) {
        int b = dst[i] >> 9;
        int lp = atomicAdd(&lfill[b], 1);
        stage[lstart[b] + lp] = make_uint2((unsigned)src[i], (unsigned)dst[i]);
    }
    __syncthreads();

    for (int i = t; i < CHUNK; i += 256) {
        uint2 p = stage[i];
        int b = (int)(p.y >> 9);
        unsigned code = p.x | ((p.y & 511u) << 17);
        epk[gbase[b] + (i - lstart[b])] = code;
    }
}

// ---------------- place: per-bucket local count+scan -> rowstart, srcs ----------------
__global__ __launch_bounds__(256) void place_kernel(const unsigned* __restrict__ epk,
                                                    const int* __restrict__ bucket_base,
                                                    int* __restrict__ rowstart,
                                                    int* __restrict__ srcs) {
    __shared__ int bufA[512];
    __shared__ int bufB[512];
    int b = blockIdx.x;
    int t = threadIdx.x;
    int pbeg = bucket_base[b];
    int pend = bucket_base[b + 1];

    bufA[t] = 0;
    bufA[t + 256] = 0;
    __syncthreads();
    for (int i = pbeg + t; i < pend; i += 256)
        atomicAdd(&bufA[epk[i] >> 17], 1);
    __syncthreads();

    for (int j = t; j < 512; j += 256) bufB[j] = j ? bufA[j - 1] : 0;
    __syncthreads();
    int* cur = bufB;
    int* nxt = bufA;
    for (int off = 1; off < 512; off <<= 1) {
        for (int j = t; j < 512; j += 256)
            nxt[j] = cur[j] + ((j >= off) ? cur[j - off] : 0);
        __syncthreads();
        int* tmp = cur; cur = nxt; nxt = tmp;
    }

    for (int j = t; j < 512; j += 256) {
        int gnode = (b << 9) + j;
        int val = pbeg + cur[j];
        if (gnode <= N_NODES) rowstart[gnode] = val;
        nxt[j] = val;
    }
    __syncthreads();

    for (int i = pbeg + t; i < pend; i += 256) {
        unsigned code = epk[i];
        int pos = atomicAdd(&nxt[code >> 17], 1);
        srcs[pos] = (int)(code & 0x1FFFFu);
    }
}

// ---------------- gather: quarter-wave per node (16 lanes x uint4), zero-row padded ----------------
// Each lane owns 8 channels (16 B) of one node; one load inst moves 1 KB across 4 rows.
// No tail loop: out-of-range edge slots read the zeroed row x_bf[N_NODES] (L1-hot, adds 0).
// No cross-lane reduction needed.
__global__ __launch_bounds__(256) void gather_kernel(const unsigned short* __restrict__ x_bf,
                                                     const int* __restrict__ rowstart,
                                                     const int* __restrict__ srcs,
                                                     unsigned short* __restrict__ aggr_bf) {
    int t = threadIdx.x;
    int node = blockIdx.x * 16 + (t >> 4);
    int l16 = t & 15;
    int begin = rowstart[node];
    int end = rowstart[node + 1];
    const unsigned short* xp = x_bf + l16 * 8;
    float a0 = 0.f, a1 = 0.f, a2 = 0.f, a3 = 0.f;
    float a4 = 0.f, a5 = 0.f, a6 = 0.f, a7 = 0.f;
    for (int e = begin; e < end; e += 8) {
        int idx[8];
#pragma unroll
        for (int i = 0; i < 8; ++i) {
            int ee = e + i;
            int ec = (ee < end) ? ee : (end - 1);   // in-bounds srcs address
            int sv = srcs[ec];
            idx[i] = (ee < end) ? sv : ZROW;        // padding slots hit zero row
        }
        uint4 u[8];
#pragma unroll
        for (int i = 0; i < 8; ++i) u[i] = *(const uint4*)(xp + (size_t)idx[i] * D);
#pragma unroll
        for (int i = 0; i < 8; ++i) {
            a0 += bf_lo(u[i].x);
            a1 += bf_hi(u[i].x);
            a2 += bf_lo(u[i].y);
            a3 += bf_hi(u[i].y);
            a4 += bf_lo(u[i].z);
            a5 += bf_hi(u[i].z);
            a6 += bf_lo(u[i].w);
            a7 += bf_hi(u[i].w);
        }
    }
    uint4 w;
    w.x = f2bf(a0) | (f2bf(a1) << 16);
    w.y = f2bf(a2) | (f2bf(a3) << 16);
    w.z = f2bf(a4) | (f2bf(a5) << 16);
    w.w = f2bf(a6) | (f2bf(a7) << 16);
    *(uint4*)(aggr_bf + (size_t)node * D + l16 * 8) = w;
}

// ---------------- MFMA GEMM + fused BN stats; h stored bf16 ----------------
#define LDSTRIDE 40
__global__ __launch_bounds__(256) void gemm_mfma(const unsigned short* __restrict__ aggr_bf,
                                                 const unsigned short* __restrict__ x_bf,
                                                 const unsigned short* __restrict__ Wt,
                                                 const float* __restrict__ brel,
                                                 unsigned short* __restrict__ h_bf,
                                                 float* __restrict__ gsum,
                                                 float* __restrict__ gss) {
    __shared__ unsigned short As[128][LDSTRIDE];
    __shared__ unsigned short Bs[128][LDSTRIDE];
    __shared__ float sbias[128];
    __shared__ float SredS[4][128];
    __shared__ float SredQ[4][128];

    const int t = threadIdx.x;
    const int wave = t >> 6;
    const int lane = t & 63;
    const int quad = lane >> 4;
    const int l16 = lane & 15;
    const int blockRow = blockIdx.x * 128;

    if (t < 128) sbias[t] = brel[t];

    f32x4 acc[2][8];
#pragma unroll
    for (int i = 0; i < 2; ++i)
#pragma unroll
        for (int j = 0; j < 8; ++j) acc[i][j] = (f32x4){0.f, 0.f, 0.f, 0.f};

    for (int kc = 0; kc < 8; ++kc) {
        const unsigned short* Asrc = (kc < 4) ? aggr_bf : x_bf;
        const int k0 = (kc & 3) * 32;
#pragma unroll
        for (int s = t; s < 512; s += 256) {
            int row = s >> 2;
            int q = (s & 3) * 8;
            int grow = blockRow + row;
            uint4 v = make_uint4(0, 0, 0, 0);
            if (grow < N_NODES) v = *(const uint4*)(Asrc + (size_t)grow * D + k0 + q);
            *(uint4*)&As[row][q] = v;
        }
#pragma unroll
        for (int s = t; s < 512; s += 256) {
            int col = s >> 2;
            int q = (s & 3) * 8;
            uint4 v = *(const uint4*)(Wt + col * 256 + kc * 32 + q);
            *(uint4*)&Bs[col][q] = v;
        }
        __syncthreads();

        bf16x8 afrag0 = *(bf16x8*)&As[wave * 32 + l16][quad * 8];
        bf16x8 afrag1 = *(bf16x8*)&As[wave * 32 + 16 + l16][quad * 8];
#pragma unroll
        for (int ct = 0; ct < 8; ++ct) {
            bf16x8 bfrag = *(bf16x8*)&Bs[ct * 16 + l16][quad * 8];
            acc[0][ct] = __builtin_amdgcn_mfma_f32_16x16x32_bf16(afrag0, bfrag, acc[0][ct], 0, 0, 0);
            acc[1][ct] = __builtin_amdgcn_mfma_f32_16x16x32_bf16(afrag1, bfrag, acc[1][ct], 0, 0, 0);
        }
        __syncthreads();
    }

    float csum[8], css[8];
#pragma unroll
    for (int ct = 0; ct < 8; ++ct) { csum[ct] = 0.f; css[ct] = 0.f; }

#pragma unroll
    for (int rt = 0; rt < 2; ++rt) {
#pragma unroll
        for (int ct = 0; ct < 8; ++ct) {
            int col = ct * 16 + l16;
            float bv = sbias[col];
#pragma unroll
            for (int reg = 0; reg < 4; ++reg) {
                int row = blockRow + wave * 32 + rt * 16 + quad * 4 + reg;
                if (row < N_NODES) {
                    float v = acc[rt][ct][reg] + bv;
                    h_bf[(size_t)row * D + col] = (unsigned short)f2bf(v);
                    csum[ct] += v;
                    css[ct] += v * v;
                }
            }
        }
    }
#pragma unroll
    for (int ct = 0; ct < 8; ++ct) {
        float s = csum[ct], q = css[ct];
        s += __shfl_xor(s, 16);
        s += __shfl_xor(s, 32);
        q += __shfl_xor(q, 16);
        q += __shfl_xor(q, 32);
        if (quad == 0) {
            SredS[wave][ct * 16 + l16] = s;
            SredQ[wave][ct * 16 + l16] = q;
        }
    }
    __syncthreads();
    if (t < 128) {
        float s = SredS[0][t] + SredS[1][t] + SredS[2][t] + SredS[3][t];
        float q = SredQ[0][t] + SredQ[1][t] + SredQ[2][t] + SredQ[3][t];
        unsafeAtomicAdd(&gsum[t], s);
        unsafeAtomicAdd(&gss[t], q);
    }
}

// ---------------- normalize + relu: read h_bf, write f32 out ----------------
__global__ __launch_bounds__(256) void norm_kernel(const unsigned short* __restrict__ h_bf,
                                                   float* __restrict__ out,
                                                   const float* __restrict__ gsum,
                                                   const float* __restrict__ gss,
                                                   const float* __restrict__ gamma,
                                                   const float* __restrict__ beta) {
    __shared__ float sscale[128];
    __shared__ float sshift[128];
    int t = threadIdx.x;
    if (t < 128) {
        const float inv_n = 1.0f / (float)N_NODES;
        float mean = gsum[t] * inv_n;
        float var = gss[t] * inv_n - mean * mean;
        float rs = rsqrtf(var + 1e-5f);
        float sc = gamma[t] * rs;
        sscale[t] = sc;
        sshift[t] = beta[t] - mean * sc;
    }
    __syncthreads();
    size_t e = ((size_t)blockIdx.x * 256 + t) * 4;
    if (e >= (size_t)N_NODES * D) return;
    int c = (int)(e & 127);
    uint2 u = *(const uint2*)(h_bf + e);
    float4 v;
    v.x = fmaxf(bf_lo(u.x) * sscale[c + 0] + sshift[c + 0], 0.f);
    v.y = fmaxf(bf_hi(u.x) * sscale[c + 1] + sshift[c + 1], 0.f);
    v.z = fmaxf(bf_lo(u.y) * sscale[c + 2] + sshift[c + 2], 0.f);
    v.w = fmaxf(bf_hi(u.y) * sscale[c + 3] + sshift[c + 3], 0.f);
    *(float4*)(out + e) = v;
}

extern "C" void kernel_launch(void* const* d_in, const int* in_sizes, int n_in,
                              void* d_out, int out_size, void* d_ws, size_t ws_size,
                              hipStream_t stream) {
    const float* x     = (const float*)d_in[0];
    const int*   ei    = (const int*)d_in[1];
    const float* Wroot = (const float*)d_in[2];
    const float* Wrel  = (const float*)d_in[3];
    const float* brel  = (const float*)d_in[4];
    const float* gamma = (const float*)d_in[5];
    const float* beta  = (const float*)d_in[6];
    float* out = (float*)d_out;

    // workspace layout; h_bf aliases (epk,srcs) which are dead by gemm time
    // x_bf has N_NODES+1 rows: row N_NODES is the zero padding row for the gather.
    unsigned short* aggr_bf = (unsigned short*)d_ws;                 // N*D (25.6 MB)
    unsigned short* x_bf    = aggr_bf + (size_t)N_NODES * D;         // (N+1)*D
    unsigned short* Wt      = x_bf + (size_t)(N_NODES + 1) * D;      // 128*256
    float* gsum  = (float*)(Wt + 128 * 256);                    // 128 ─┐
    float* gss   = gsum + 128;                                  // 128  │ zeroed
    int* bcount  = (int*)(gss + 128);                           // 256 ─┘
    int* bucket_base = bcount + 256;                            // 256 (197 used)
    int* bcur    = bucket_base + 256;                           // 256
    int* rowstart = bcur + 256;                                 // 100352
    unsigned* epk = (unsigned*)(rowstart + 100352);             // N_EDGES (6.4 MB)
    int* srcs    = (int*)(epk + N_EDGES);                       // N_EDGES (6.4 MB)
    unsigned short* h_bf = (unsigned short*)epk;                // N*D (25.6 MB) alias

    hipMemsetAsync(gsum, 0, 512 * sizeof(int), stream);

    prep_kernel<<<CVT_X_BLOCKS + 129 + BIN_BLOCKS, 256, 0, stream>>>(
        x, Wrel, Wroot, ei, x_bf, Wt, bcount);
    bscan_kernel<<<1, 256, 0, stream>>>(bcount, bucket_base, bcur);
    binify_kernel<<<BIN_BLOCKS, 256, 0, stream>>>(ei, bcur, epk);
    place_kernel<<<NB, 256, 0, stream>>>(epk, bucket_base, rowstart, srcs);
    gather_kernel<<<N_NODES / 16, 256, 0, stream>>>(x_bf, rowstart, srcs, aggr_bf);
    gemm_mfma<<<(N_NODES + 127) / 128, 256, 0, stream>>>(aggr_bf, x_bf, Wt, brel, h_bf, gsum, gss);
    norm_kernel<<<12500, 256, 0, stream>>>(h_bf, out, gsum, gss, gamma, beta);
}

// Round 3
// 282.853 us; speedup vs baseline: 1.0629x; 1.0175x over previous
//
#include <hip/hip_runtime.h>

#define N_NODES 100000
#define N_EDGES 1600000
#define D 128
#define NB 196              // buckets of 512 nodes: 196*512 = 100352 >= N_NODES
#define EPT 10              // edges per thread in binning
#define CHUNK 2560          // 256 threads * EPT
#define BIN_BLOCKS 625      // 625 * 2560 = 1,600,000 exactly
#define CVT_X_BLOCKS 6250   // 6250*256*8 = 12.8M elements
#define ZROW N_NODES        // index of the zeroed padding row in x_bf

typedef __bf16 bf16x8 __attribute__((ext_vector_type(8)));
typedef float f32x4 __attribute__((ext_vector_type(4)));

__device__ __forceinline__ unsigned f2bf(float f) {
    unsigned u = __float_as_uint(f);
    return (u + 0x7fffu + ((u >> 16) & 1u)) >> 16;   // RNE
}
__device__ __forceinline__ float bf_lo(unsigned u) { return __uint_as_float(u << 16); }
__device__ __forceinline__ float bf_hi(unsigned u) { return __uint_as_float(u & 0xffff0000u); }

// ---------------- fused: x->bf16 (row-major) + Wt build + zero-row + bucket histogram ----------------
__global__ __launch_bounds__(256) void prep_kernel(const float* __restrict__ x,
                                                   const float* __restrict__ Wrel,
                                                   const float* __restrict__ Wroot,
                                                   const int* __restrict__ ei,
                                                   unsigned short* __restrict__ x_bf,
                                                   unsigned short* __restrict__ Wt,
                                                   int* __restrict__ bcount) {
    __shared__ int h[256];
    int b = blockIdx.x;
    int t = threadIdx.x;
    if (b < CVT_X_BLOCKS) {
        size_t i = ((size_t)b * 256 + t) * 8;
        float4 v0 = *(const float4*)(x + i);
        float4 v1 = *(const float4*)(x + i + 4);
        uint4 p;
        p.x = f2bf(v0.x) | (f2bf(v0.y) << 16);
        p.y = f2bf(v0.z) | (f2bf(v0.w) << 16);
        p.z = f2bf(v1.x) | (f2bf(v1.y) << 16);
        p.w = f2bf(v1.z) | (f2bf(v1.w) << 16);
        *(uint4*)(x_bf + i) = p;
    } else if (b < CVT_X_BLOCKS + 128) {
        int c = b - CVT_X_BLOCKS;          // 0..127
        float v = (t < 128) ? Wrel[t * D + c] : Wroot[(t - 128) * D + c];
        Wt[c * 256 + t] = (unsigned short)f2bf(v);
    } else if (b == CVT_X_BLOCKS + 128) {
        // zero the padding row x_bf[N_NODES]: 128 shorts = 16 uint4
        if (t < 16) *(uint4*)(x_bf + (size_t)ZROW * D + t * 8) = make_uint4(0, 0, 0, 0);
    } else {
        int blk = b - (CVT_X_BLOCKS + 129);
        h[t] = 0;
        __syncthreads();
        int base = blk * CHUNK;
#pragma unroll
        for (int i = 0; i < EPT; ++i) {
            int dst = ei[N_EDGES + base + i * 256 + t];
            atomicAdd(&h[dst >> 9], 1);
        }
        __syncthreads();
        if (t < NB && h[t]) atomicAdd(&bcount[t], h[t]);
    }
}

// ---------------- bucket scan (1 block) ----------------
__global__ __launch_bounds__(256) void bscan_kernel(const int* __restrict__ bcount,
                                                    int* __restrict__ bucket_base,
                                                    int* __restrict__ bcur) {
    __shared__ int s[256];
    int t = threadIdx.x;
    int v = (t < NB) ? bcount[t] : 0;
    s[t] = v;
    __syncthreads();
    for (int off = 1; off < 256; off <<= 1) {
        int a = (t >= off) ? s[t - off] : 0;
        __syncthreads();
        s[t] += a;
        __syncthreads();
    }
    int excl = s[t] - v;
    if (t < NB) {
        bucket_base[t] = excl;
        bcur[t] = excl;
    }
    if (t == NB) bucket_base[NB] = N_EDGES;
}

// ---------------- binify: block-local multisplit -> packed 4B edge codes ----------------
// code: src in bits 0..16, local dst (dst&511) in bits 17..25
__global__ __launch_bounds__(256) void binify_kernel(const int* __restrict__ ei,
                                                     int* __restrict__ bcur,
                                                     unsigned* __restrict__ epk) {
    __shared__ int lhist[256];
    __shared__ int lstart[256];
    __shared__ int lfill[256];
    __shared__ int gbase[256];
    __shared__ uint2 stage[CHUNK];

    int t = threadIdx.x;
    int base = blockIdx.x * CHUNK;
    lhist[t] = 0;
    lfill[t] = 0;
    __syncthreads();

    int src[EPT], dst[EPT];
#pragma unroll
    for (int i = 0; i < EPT; ++i) {
        int e = base + i * 256 + t;
        src[i] = ei[e];
        dst[i] = ei[N_EDGES + e];
        atomicAdd(&lhist[dst[i] >> 9], 1);
    }
    __syncthreads();

    int v = lhist[t];
    lstart[t] = v;
    __syncthreads();
    for (int off = 1; off < 256; off <<= 1) {
        int a = (t >= off) ? lstart[t - off] : 0;
        __syncthreads();
        lstart[t] += a;
        __syncthreads();
    }
    int excl = lstart[t] - v;
    if (t < NB && v > 0) gbase[t] = atomicAdd(&bcur[t], v);
    __syncthreads();
    lstart[t] = excl;
    __syncthreads();

#pragma unroll
    for (int i = 0; i < EPT; ++i) {
        int b = dst[i] >> 9;
        int lp = atomicAdd(&lfill[b], 1);
        stage[lstart[b] + lp] = make_uint2((unsigned)src[i], (unsigned)dst[i]);
    }
    __syncthreads();

    for (int i = t; i < CHUNK; i += 256) {
        uint2 p = stage[i];
        int b = (int)(p.y >> 9);
        unsigned code = p.x | ((p.y & 511u) << 17);
        epk[gbase[b] + (i - lstart[b])] = code;
    }
}

// ---------------- place: per-bucket local count+scan -> rowstart, srcs ----------------
__global__ __launch_bounds__(256) void place_kernel(const unsigned* __restrict__ epk,
                                                    const int* __restrict__ bucket_base,
                                                    int* __restrict__ rowstart,
                                                    int* __restrict__ srcs) {
    __shared__ int bufA[512];
    __shared__ int bufB[512];
    int b = blockIdx.x;
    int t = threadIdx.x;
    int pbeg = bucket_base[b];
    int pend = bucket_base[b + 1];

    bufA[t] = 0;
    bufA[t + 256] = 0;
    __syncthreads();
    for (int i = pbeg + t; i < pend; i += 256)
        atomicAdd(&bufA[epk[i] >> 17], 1);
    __syncthreads();

    for (int j = t; j < 512; j += 256) bufB[j] = j ? bufA[j - 1] : 0;
    __syncthreads();
    int* cur = bufB;
    int* nxt = bufA;
    for (int off = 1; off < 512; off <<= 1) {
        for (int j = t; j < 512; j += 256)
            nxt[j] = cur[j] + ((j >= off) ? cur[j - off] : 0);
        __syncthreads();
        int* tmp = cur; cur = nxt; nxt = tmp;
    }

    for (int j = t; j < 512; j += 256) {
        int gnode = (b << 9) + j;
        int val = pbeg + cur[j];
        if (gnode <= N_NODES) rowstart[gnode] = val;
        nxt[j] = val;
    }
    __syncthreads();

    for (int i = pbeg + t; i < pend; i += 256) {
        unsigned code = epk[i];
        int pos = atomicAdd(&nxt[code >> 17], 1);
        srcs[pos] = (int)(code & 0x1FFFFu);
    }
}

// ---------------- gather: quarter-wave per node (16 lanes x uint4), zero-row padded ----------------
__global__ __launch_bounds__(256) void gather_kernel(const unsigned short* __restrict__ x_bf,
                                                     const int* __restrict__ rowstart,
                                                     const int* __restrict__ srcs,
                                                     unsigned short* __restrict__ aggr_bf) {
    int t = threadIdx.x;
    int node = blockIdx.x * 16 + (t >> 4);
    int l16 = t & 15;
    int begin = rowstart[node];
    int end = rowstart[node + 1];
    const unsigned short* xp = x_bf + l16 * 8;
    float a0 = 0.f, a1 = 0.f, a2 = 0.f, a3 = 0.f;
    float a4 = 0.f, a5 = 0.f, a6 = 0.f, a7 = 0.f;
    for (int e = begin; e < end; e += 8) {
        int idx[8];
#pragma unroll
        for (int i = 0; i < 8; ++i) {
            int ee = e + i;
            int ec = (ee < end) ? ee : (end - 1);   // in-bounds srcs address
            int sv = srcs[ec];
            idx[i] = (ee < end) ? sv : ZROW;        // padding slots hit zero row
        }
        uint4 u[8];
#pragma unroll
        for (int i = 0; i < 8; ++i) u[i] = *(const uint4*)(xp + (size_t)idx[i] * D);
#pragma unroll
        for (int i = 0; i < 8; ++i) {
            a0 += bf_lo(u[i].x);
            a1 += bf_hi(u[i].x);
            a2 += bf_lo(u[i].y);
            a3 += bf_hi(u[i].y);
            a4 += bf_lo(u[i].z);
            a5 += bf_hi(u[i].z);
            a6 += bf_lo(u[i].w);
            a7 += bf_hi(u[i].w);
        }
    }
    uint4 w;
    w.x = f2bf(a0) | (f2bf(a1) << 16);
    w.y = f2bf(a2) | (f2bf(a3) << 16);
    w.z = f2bf(a4) | (f2bf(a5) << 16);
    w.w = f2bf(a6) | (f2bf(a7) << 16);
    *(uint4*)(aggr_bf + (size_t)node * D + l16 * 8) = w;
}

// ---------------- MFMA GEMM + fused BN stats; h stored bf16 ----------------
// Barrier-light: A-fragments loaded DIRECTLY from global (row-major, k contiguous);
// B staged once per 128-k half into fragment-major LDS (lane-contiguous ds_read_b128
// => zero bank conflicts). 3 barriers total instead of 16.
__global__ __launch_bounds__(256) void gemm_mfma(const unsigned short* __restrict__ aggr_bf,
                                                 const unsigned short* __restrict__ x_bf,
                                                 const unsigned short* __restrict__ Wt,
                                                 const float* __restrict__ brel,
                                                 unsigned short* __restrict__ h_bf,
                                                 float* __restrict__ gsum,
                                                 float* __restrict__ gss) {
    // Bf[kc(4)][ct(8)][lane(64)][8 shorts] = 2048 fragments * 16B = 32 KB
    __shared__ unsigned short Bf[2048 * 8];
    __shared__ float sbias[128];
    __shared__ float SredS[4][128];
    __shared__ float SredQ[4][128];

    const int t = threadIdx.x;
    const int wave = t >> 6;
    const int lane = t & 63;
    const int quad = lane >> 4;
    const int l16 = lane & 15;
    const int blockRow = blockIdx.x * 128;

    if (t < 128) sbias[t] = brel[t];

    f32x4 acc[2][8];
#pragma unroll
    for (int i = 0; i < 2; ++i)
#pragma unroll
        for (int j = 0; j < 8; ++j) acc[i][j] = (f32x4){0.f, 0.f, 0.f, 0.f};

    const int rowb = blockRow + wave * 32;

#pragma unroll
    for (int half = 0; half < 2; ++half) {
        // stage B fragments for this 128-k half: frag f = (kcl*8+ct)*64 + ln
        // holds Wt[col(ln,ct)*256 + half*128 + kcl*32 + (ln>>4)*8 .. +7]
#pragma unroll
        for (int f = t; f < 2048; f += 256) {
            int kcl = f >> 9;
            int ct = (f >> 6) & 7;
            int ln = f & 63;
            int col = ct * 16 + (ln & 15);
            int kb = half * 128 + kcl * 32 + ((ln >> 4) << 3);
            *(uint4*)&Bf[f * 8] = *(const uint4*)(Wt + col * 256 + kb);
        }
        __syncthreads();

        const unsigned short* Asrc = half ? x_bf : aggr_bf;
#pragma unroll
        for (int kcl = 0; kcl < 4; ++kcl) {
            const int k0 = kcl * 32 + quad * 8;
            bf16x8 af0 = *(const bf16x8*)(Asrc + (size_t)(rowb + l16) * D + k0);
            bf16x8 af1 = *(const bf16x8*)(Asrc + (size_t)(rowb + 16 + l16) * D + k0);
#pragma unroll
            for (int ct = 0; ct < 8; ++ct) {
                bf16x8 bfrag = *(const bf16x8*)&Bf[((kcl * 8 + ct) * 64 + lane) * 8];
                acc[0][ct] = __builtin_amdgcn_mfma_f32_16x16x32_bf16(af0, bfrag, acc[0][ct], 0, 0, 0);
                acc[1][ct] = __builtin_amdgcn_mfma_f32_16x16x32_bf16(af1, bfrag, acc[1][ct], 0, 0, 0);
            }
        }
        if (half == 0) __syncthreads();   // all waves done reading half-0 fragments
    }

    float csum[8], css[8];
#pragma unroll
    for (int ct = 0; ct < 8; ++ct) { csum[ct] = 0.f; css[ct] = 0.f; }

#pragma unroll
    for (int rt = 0; rt < 2; ++rt) {
#pragma unroll
        for (int ct = 0; ct < 8; ++ct) {
            int col = ct * 16 + l16;
            float bv = sbias[col];
#pragma unroll
            for (int reg = 0; reg < 4; ++reg) {
                int row = blockRow + wave * 32 + rt * 16 + quad * 4 + reg;
                if (row < N_NODES) {
                    float v = acc[rt][ct][reg] + bv;
                    h_bf[(size_t)row * D + col] = (unsigned short)f2bf(v);
                    csum[ct] += v;
                    css[ct] += v * v;
                }
            }
        }
    }
#pragma unroll
    for (int ct = 0; ct < 8; ++ct) {
        float s = csum[ct], q = css[ct];
        s += __shfl_xor(s, 16);
        s += __shfl_xor(s, 32);
        q += __shfl_xor(q, 16);
        q += __shfl_xor(q, 32);
        if (quad == 0) {
            SredS[wave][ct * 16 + l16] = s;
            SredQ[wave][ct * 16 + l16] = q;
        }
    }
    __syncthreads();
    if (t < 128) {
        float s = SredS[0][t] + SredS[1][t] + SredS[2][t] + SredS[3][t];
        float q = SredQ[0][t] + SredQ[1][t] + SredQ[2][t] + SredQ[3][t];
        unsafeAtomicAdd(&gsum[t], s);
        unsafeAtomicAdd(&gss[t], q);
    }
}

// ---------------- normalize + relu: read h_bf, write f32 out ----------------
__global__ __launch_bounds__(256) void norm_kernel(const unsigned short* __restrict__ h_bf,
                                                   float* __restrict__ out,
                                                   const float* __restrict__ gsum,
                                                   const float* __restrict__ gss,
                                                   const float* __restrict__ gamma,
                                                   const float* __restrict__ beta) {
    __shared__ float sscale[128];
    __shared__ float sshift[128];
    int t = threadIdx.x;
    if (t < 128) {
        const float inv_n = 1.0f / (float)N_NODES;
        float mean = gsum[t] * inv_n;
        float var = gss[t] * inv_n - mean * mean;
        float rs = rsqrtf(var + 1e-5f);
        float sc = gamma[t] * rs;
        sscale[t] = sc;
        sshift[t] = beta[t] - mean * sc;
    }
    __syncthreads();
    size_t e = ((size_t)blockIdx.x * 256 + t) * 4;
    if (e >= (size_t)N_NODES * D) return;
    int c = (int)(e & 127);
    uint2 u = *(const uint2*)(h_bf + e);
    float4 v;
    v.x = fmaxf(bf_lo(u.x) * sscale[c + 0] + sshift[c + 0], 0.f);
    v.y = fmaxf(bf_hi(u.x) * sscale[c + 1] + sshift[c + 1], 0.f);
    v.z = fmaxf(bf_lo(u.y) * sscale[c + 2] + sshift[c + 2], 0.f);
    v.w = fmaxf(bf_hi(u.y) * sscale[c + 3] + sshift[c + 3], 0.f);
    *(float4*)(out + e) = v;
}

extern "C" void kernel_launch(void* const* d_in, const int* in_sizes, int n_in,
                              void* d_out, int out_size, void* d_ws, size_t ws_size,
                              hipStream_t stream) {
    const float* x     = (const float*)d_in[0];
    const int*   ei    = (const int*)d_in[1];
    const float* Wroot = (const float*)d_in[2];
    const float* Wrel  = (const float*)d_in[3];
    const float* brel  = (const float*)d_in[4];
    const float* gamma = (const float*)d_in[5];
    const float* beta  = (const float*)d_in[6];
    float* out = (float*)d_out;

    // workspace layout; h_bf aliases (epk,srcs) which are dead by gemm time
    // x_bf has N_NODES+1 rows: row N_NODES is the zero padding row for the gather.
    unsigned short* aggr_bf = (unsigned short*)d_ws;                 // N*D (25.6 MB)
    unsigned short* x_bf    = aggr_bf + (size_t)N_NODES * D;         // (N+1)*D
    unsigned short* Wt      = x_bf + (size_t)(N_NODES + 1) * D;      // 128*256
    float* gsum  = (float*)(Wt + 128 * 256);                    // 128 ─┐
    float* gss   = gsum + 128;                                  // 128  │ zeroed
    int* bcount  = (int*)(gss + 128);                           // 256 ─┘
    int* bucket_base = bcount + 256;                            // 256 (197 used)
    int* bcur    = bucket_base + 256;                           // 256
    int* rowstart = bcur + 256;                                 // 100352
    unsigned* epk = (unsigned*)(rowstart + 100352);             // N_EDGES (6.4 MB)
    int* srcs    = (int*)(epk + N_EDGES);                       // N_EDGES (6.4 MB)
    unsigned short* h_bf = (unsigned short*)epk;                // N*D (25.6 MB) alias

    hipMemsetAsync(gsum, 0, 512 * sizeof(int), stream);

    prep_kernel<<<CVT_X_BLOCKS + 129 + BIN_BLOCKS, 256, 0, stream>>>(
        x, Wrel, Wroot, ei, x_bf, Wt, bcount);
    bscan_kernel<<<1, 256, 0, stream>>>(bcount, bucket_base, bcur);
    binify_kernel<<<BIN_BLOCKS, 256, 0, stream>>>(ei, bcur, epk);
    place_kernel<<<NB, 256, 0, stream>>>(epk, bucket_base, rowstart, srcs);
    gather_kernel<<<N_NODES / 16, 256, 0, stream>>>(x_bf, rowstart, srcs, aggr_bf);
    gemm_mfma<<<(N_NODES + 127) / 128, 256, 0, stream>>>(aggr_bf, x_bf, Wt, brel, h_bf, gsum, gss);
    norm_kernel<<<12500, 256, 0, stream>>>(h_bf, out, gsum, gss, gamma, beta);
}